// Round 17
// baseline (204.172 us; speedup 1.0000x reference)
//
#include <hip/hip_runtime.h>

#define DIM 128
#define SCAN_BLK 1024

// round-to-nearest-even f32 -> bf16 bits
__device__ __forceinline__ unsigned short bf16rn(float f) {
    unsigned u = __float_as_uint(f);
    u += 0x7fffu + ((u >> 16) & 1u);
    return (unsigned short)(u >> 16);
}

// ---- per-node dot + bf16 row conversion; also zeroes cnt (replaces memset) ----
__global__ void k_prep(const float* __restrict__ u_emb, const float* __restrict__ i_emb,
                       const float* __restrict__ attn_w, float* __restrict__ sdot,
                       ushort2* __restrict__ bemb, unsigned* __restrict__ cnt,
                       int nu, int n, int do_bf16) {
    int tid = blockIdx.x * blockDim.x + threadIdx.x;
    if (tid < n) cnt[tid] = 0u;              // grid has >= n threads (64 per node)
    int gw = tid >> 6;
    int lane = threadIdx.x & 63;
    if (gw >= n) return;
    const bool isU = gw < nu;
    const float2* row = (const float2*)(isU ? u_emb + (size_t)gw * DIM
                                            : i_emb + (size_t)(gw - nu) * DIM);
    const float2* wv  = (const float2*)(isU ? attn_w : attn_w + DIM);
    float2 a = row[lane];
    float2 b = wv[lane];
    float v = a.x * b.x + a.y * b.y;
    #pragma unroll
    for (int off = 32; off; off >>= 1) v += __shfl_down(v, off);
    if (lane == 0) sdot[gw] = v;
    if (do_bf16) {
        ushort2 h;
        h.x = bf16rn(a.x);
        h.y = bf16rn(a.y);
        bemb[(size_t)gw * (DIM / 2) + lane] = h;
    }
}

// ---- per-edge degree histogram; atomic return value = rank within node list ----
__global__ void k_count(const int* __restrict__ uidx, const int* __restrict__ iidx,
                        unsigned* __restrict__ cnt, unsigned* __restrict__ ranks,
                        int nu, int ne) {
    int e = blockIdx.x * blockDim.x + threadIdx.x;
    if (e >= ne) return;
    unsigned r0 = atomicAdd(&cnt[uidx[e]], 1u);
    unsigned r1 = atomicAdd(&cnt[nu + iidx[e]], 1u);
    ranks[e] = (r0 << 16) | (r1 & 0xffffu);
}

// ---- two-level scan ----
__global__ void k_scan1(const unsigned* __restrict__ cnt, unsigned* __restrict__ incl,
                        unsigned* __restrict__ bsum, int n) {
    __shared__ unsigned part[SCAN_BLK];
    int t = threadIdx.x;
    int j = blockIdx.x * SCAN_BLK + t;
    unsigned v = (j < n) ? cnt[j] : 0u;
    part[t] = v;
    __syncthreads();
    for (int d = 1; d < SCAN_BLK; d <<= 1) {
        unsigned w = (t >= d) ? part[t - d] : 0u;
        __syncthreads();
        part[t] += w;
        __syncthreads();
    }
    if (j < n) incl[j] = part[t];
    if (t == SCAN_BLK - 1) bsum[blockIdx.x] = part[t];
}

__global__ void k_scan2(unsigned* __restrict__ bsum, int nb) {
    __shared__ unsigned part[SCAN_BLK];
    int t = threadIdx.x;
    unsigned v = (t < nb) ? bsum[t] : 0u;
    part[t] = v;
    __syncthreads();
    for (int d = 1; d < SCAN_BLK; d <<= 1) {
        unsigned w = (t >= d) ? part[t - d] : 0u;
        __syncthreads();
        part[t] += w;
        __syncthreads();
    }
    if (t < nb) bsum[t] = part[t] - v;   // exclusive prefix
}

__global__ void k_scan3(const unsigned* __restrict__ cnt, const unsigned* __restrict__ incl,
                        const unsigned* __restrict__ bsum,
                        unsigned* __restrict__ off, int n) {
    int j = blockIdx.x * blockDim.x + threadIdx.x;
    if (j >= n) return;
    off[j] = incl[j] - cnt[j] + bsum[j / SCAN_BLK];
}

// ---- per-edge CSR fill: neighbor CONCAT index, rank-addressed (no atomics) ----
__global__ void k_fill(const int* __restrict__ uidx, const int* __restrict__ iidx,
                       const unsigned* __restrict__ off, const unsigned* __restrict__ ranks,
                       int* __restrict__ nbr, int nu, int ne) {
    int e = blockIdx.x * blockDim.x + threadIdx.x;
    if (e >= ne) return;
    int u = uidx[e], i = iidx[e];
    unsigned rk = ranks[e];
    nbr[off[u]      + (rk >> 16)]     = nu + i;
    nbr[off[nu + i] + (rk & 0xffffu)] = u;
}

// ---- persistent-wave accum, TWO nodes per wave interleaved (2x MLP),
// quarter-wave gathers: 16 lanes per neighbor row, uint4 loads.
__global__ void k_accum_bf16(const float* __restrict__ u_emb, const float* __restrict__ i_emb,
                             const uint4* __restrict__ bemb, const float* __restrict__ sdot,
                             const unsigned* __restrict__ off, const unsigned* __restrict__ cnt,
                             const int* __restrict__ nbr,
                             float* __restrict__ out, int nu, int n) {
    int wid  = (blockIdx.x * blockDim.x + threadIdx.x) >> 6;
    int lane = threadIdx.x & 63;
    int nwav = (gridDim.x * blockDim.x) >> 6;
    int q = lane >> 4, l16 = lane & 15;
    int step = 2 * nwav;

    int nodeA = wid;
    int nodeB = wid + nwav;
    if (nodeA >= n) return;

    // front-end loader
    auto loadFE = [&](int node, unsigned& s, unsigned& d, float& ss, int& o, float& sd) {
        s = off[node]; d = cnt[node]; ss = sdot[node];
        o = 0; sd = 0.f;
        unsigned dc = d < 64u ? d : 64u;
        if ((unsigned)lane < dc) { o = nbr[s + lane]; sd = sdot[o]; }
    };

    unsigned sA, dA, sB = 0, dB = 0;
    float ssA, ssB = 0.f;
    int oA, oB = 0;
    float sdA, sdB = 0.f;
    loadFE(nodeA, sA, dA, ssA, oA, sdA);
    if (nodeB < n) loadFE(nodeB, sB, dB, ssB, oB, sdB);

    while (true) {
        // prefetch next pair
        int nA = nodeA + step, nB = nodeB + step;
        unsigned snA = 0, dnA = 0, snB = 0, dnB = 0;
        float ssnA = 0.f, ssnB = 0.f, sdnA = 0.f, sdnB = 0.f;
        int onA = 0, onB = 0;
        if (nA < n) loadFE(nA, snA, dnA, ssnA, onA, sdnA);
        if (nB < n) loadFE(nB, snB, dnB, ssnB, onB, sdnB);

        float accA[8] = {0,0,0,0,0,0,0,0}, accB[8] = {0,0,0,0,0,0,0,0};
        float wsumA = 0.f, wsumB = 0.f;

        // weights (first chunk, prefetched)
        unsigned mA = dA < 64u ? dA : 64u;
        unsigned mB = dB < 64u ? dB : 64u;
        float wA = 0.f, wB = 0.f;
        if ((unsigned)lane < mA) {
            float r = ssA + sdA; r = fmaxf(r, 0.2f * r); wA = __expf(r);
        }
        if ((unsigned)lane < mB) {
            float r = ssB + sdB; r = fmaxf(r, 0.2f * r); wB = __expf(r);
        }

        auto doQuad = [&](int oArr, float wArr, unsigned srcIdx, bool active,
                          float* acc, float& wsum) {
            int   oj = __shfl(oArr, (int)srcIdx);
            float wj = __shfl(wArr, (int)srcIdx);
            if (active) {
                uint4 h = bemb[(size_t)oj * (DIM / 8) + l16];
                wsum += wj;
                acc[0] += wj * __uint_as_float(h.x << 16);
                acc[1] += wj * __uint_as_float(h.x & 0xffff0000u);
                acc[2] += wj * __uint_as_float(h.y << 16);
                acc[3] += wj * __uint_as_float(h.y & 0xffff0000u);
                acc[4] += wj * __uint_as_float(h.z << 16);
                acc[5] += wj * __uint_as_float(h.z & 0xffff0000u);
                acc[6] += wj * __uint_as_float(h.w << 16);
                acc[7] += wj * __uint_as_float(h.w & 0xffff0000u);
            }
        };

        // interleaved quad loop over both nodes: 2 independent gathers in flight
        unsigned mx = mA > mB ? mA : mB;
        #pragma unroll 2
        for (unsigned j = 0; j < mx; j += 4) {
            unsigned src = j + (unsigned)q;
            doQuad(oA, wA, src, src < mA, accA, wsumA);
            doQuad(oB, wB, src, src < mB, accB, wsumB);
        }

        // tail chunks for d > 64 (rare), sequential per node
        for (unsigned base = 64; base < dA; base += 64) {
            unsigned chunk = dA - base; if (chunk > 64) chunk = 64;
            int o2 = 0; float w2 = 0.f;
            if ((unsigned)lane < chunk) {
                o2 = nbr[sA + base + lane];
                float r = ssA + sdot[o2]; r = fmaxf(r, 0.2f * r); w2 = __expf(r);
            }
            for (unsigned jj = 0; jj < chunk; jj += 4) {
                unsigned src = jj + (unsigned)q;
                doQuad(o2, w2, src, src < chunk, accA, wsumA);
            }
        }
        for (unsigned base = 64; base < dB; base += 64) {
            unsigned chunk = dB - base; if (chunk > 64) chunk = 64;
            int o2 = 0; float w2 = 0.f;
            if ((unsigned)lane < chunk) {
                o2 = nbr[sB + base + lane];
                float r = ssB + sdot[o2]; r = fmaxf(r, 0.2f * r); w2 = __expf(r);
            }
            for (unsigned jj = 0; jj < chunk; jj += 4) {
                unsigned src = jj + (unsigned)q;
                doQuad(o2, w2, src, src < chunk, accB, wsumB);
            }
        }

        // combine the 4 quarter-wave partials for both nodes
        #pragma unroll
        for (int m = 16; m <= 32; m <<= 1) {
            wsumA += __shfl_xor(wsumA, m);
            wsumB += __shfl_xor(wsumB, m);
            #pragma unroll
            for (int k = 0; k < 8; ++k) {
                accA[k] += __shfl_xor(accA[k], m);
                accB[k] += __shfl_xor(accB[k], m);
            }
        }

        auto writeRow = [&](int node, const float* acc, float wsum) {
            float inv = 1.f / (wsum + 1e-10f);
            const float* self = (node < nu) ? u_emb + (size_t)node * DIM
                                            : i_emb + (size_t)(node - nu) * DIM;
            const float4* sr = (const float4*)self;
            float4 s0 = sr[2 * l16];
            float4 s1 = sr[2 * l16 + 1];
            s0.x += acc[0] * inv; s0.y += acc[1] * inv;
            s0.z += acc[2] * inv; s0.w += acc[3] * inv;
            s1.x += acc[4] * inv; s1.y += acc[5] * inv;
            s1.z += acc[6] * inv; s1.w += acc[7] * inv;
            float4* orow = (float4*)(out + (size_t)node * DIM);
            orow[2 * l16]     = s0;
            orow[2 * l16 + 1] = s1;
        };
        if (q == 0) {
            writeRow(nodeA, accA, wsumA);
            if (nodeB < n) writeRow(nodeB, accB, wsumB);
        }

        if (nA >= n) break;
        nodeA = nA; nodeB = nB;
        sA = snA; dA = dnA; ssA = ssnA; oA = onA; sdA = sdnA;
        sB = snB; dB = dnB; ssB = ssnB; oB = onB; sdB = sdnB;
    }
}

// ---- fallback (no bf16 scratch): float2-per-lane, f32 gathers, CSR layout ----
__global__ void k_accum_f32(const float* __restrict__ u_emb, const float* __restrict__ i_emb,
                            const float* __restrict__ sdot,
                            const unsigned* __restrict__ off, const unsigned* __restrict__ cnt,
                            const int* __restrict__ nbr,
                            float* __restrict__ out, int nu, int n) {
    int gw = (blockIdx.x * blockDim.x + threadIdx.x) >> 6;
    int lane = threadIdx.x & 63;
    if (gw >= n) return;
    float sd_self = sdot[gw];
    unsigned s = off[gw];
    unsigned d = cnt[gw];
    float2 acc = make_float2(0.f, 0.f);
    float wsum = 0.f;
    for (unsigned base = 0; base < d; base += 64) {
        unsigned chunk = d - base; if (chunk > 64) chunk = 64;
        int   o = 0;
        float w = 0.f;
        if (lane < (int)chunk) {
            o = nbr[s + base + lane];
            float r = sd_self + sdot[o];
            r = fmaxf(r, 0.2f * r);
            w = __expf(r);
        }
        for (unsigned j = 0; j < chunk; ++j) {
            int   oj = __shfl(o, (int)j);
            float wj = __shfl(w, (int)j);
            const float* base_ = (oj < nu) ? u_emb + (size_t)oj * DIM
                                           : i_emb + (size_t)(oj - nu) * DIM;
            float2 vj = ((const float2*)base_)[lane];
            wsum += wj;
            acc.x += wj * vj.x;
            acc.y += wj * vj.y;
        }
    }
    float inv = 1.f / (wsum + 1e-10f);
    const float* self = (gw < nu) ? u_emb + (size_t)gw * DIM
                                  : i_emb + (size_t)(gw - nu) * DIM;
    float2 sv = ((const float2*)self)[lane];
    sv.x += acc.x * inv;
    sv.y += acc.y * inv;
    ((float2*)(out + (size_t)gw * DIM))[lane] = sv;
}

extern "C" void kernel_launch(void* const* d_in, const int* in_sizes, int n_in,
                              void* d_out, int out_size, void* d_ws, size_t ws_size,
                              hipStream_t stream) {
    const float* u_emb  = (const float*)d_in[0];
    const float* i_emb  = (const float*)d_in[1];
    const int*   edge   = (const int*)d_in[2];
    // d_in[3] = weights, unused by the reference
    const float* attn_w = (const float*)d_in[4];

    const int nu = in_sizes[0] / DIM;
    const int ni = in_sizes[1] / DIM;
    const int ne = in_sizes[3];
    const int n  = nu + ni;

    const int* uidx = edge;
    const int* iidx = edge + ne;

    float* out = (float*)d_out;   // rows [0,nu) = new_u, rows [nu,n) = new_i

    char* ws = (char*)d_ws;
    size_t used = 0;
    auto take = [&](size_t bytes) {
        char* p = ws + used;
        used += (bytes + 15) & ~size_t(15);
        return p;
    };
    float*    sdot  = (float*)   take((size_t)n * sizeof(float));
    unsigned* cnt   = (unsigned*)take((size_t)n * sizeof(unsigned));
    unsigned* off   = (unsigned*)take((size_t)n * sizeof(unsigned));
    unsigned* incl  = (unsigned*)take((size_t)n * sizeof(unsigned));
    unsigned* bsum  = (unsigned*)take((size_t)SCAN_BLK * sizeof(unsigned));
    unsigned* ranks = (unsigned*)take((size_t)ne * sizeof(unsigned));
    int*      nbr   = (int*)     take((size_t)2 * ne * sizeof(int));
    size_t bembBytes = (size_t)n * DIM * 2;          // bf16 concat table (38.4 MB)
    const int do_bf16 = (used + bembBytes <= ws_size) ? 1 : 0;
    void* bemb = do_bf16 ? (void*)take(bembBytes) : nullptr;

    const int nb = (n + SCAN_BLK - 1) / SCAN_BLK;   // 147 for n=150k

    // 1. prep: per-node dots + bf16 conversion + cnt zeroing (streaming)
    k_prep<<<(n + 3) / 4, 256, 0, stream>>>(u_emb, i_emb, attn_w, sdot,
                                            (ushort2*)bemb, cnt, nu, n, do_bf16);

    // 2. degree histogram with per-edge ranks (L2-resident atomics, isolated)
    k_count<<<(ne + 255) / 256, 256, 0, stream>>>(uidx, iidx, cnt, ranks, nu, ne);

    // 3. CSR offsets via two-level scan
    k_scan1<<<nb, SCAN_BLK, 0, stream>>>(cnt, incl, bsum, n);
    k_scan2<<<1, SCAN_BLK, 0, stream>>>(bsum, nb);
    k_scan3<<<(n + 255) / 256, 256, 0, stream>>>(cnt, incl, bsum, off, n);

    // 4. CSR fill at off+rank (no atomics; isolated from streaming)
    k_fill<<<(ne + 255) / 256, 256, 0, stream>>>(uidx, iidx, off, ranks, nbr, nu, ne);

    // 5. gather-accumulate: persistent waves, 2 nodes/wave interleaved, prefetch
    if (do_bf16)
        k_accum_bf16<<<2048, 256, 0, stream>>>(u_emb, i_emb, (const uint4*)bemb,
                                               sdot, off, cnt, nbr, out, nu, n);
    else
        k_accum_f32<<<(n + 3) / 4, 256, 0, stream>>>(u_emb, i_emb, sdot, off, cnt,
                                                     nbr, out, nu, n);
}

// Round 18
// 173.599 us; speedup vs baseline: 1.1761x; 1.1761x over previous
//
#include <hip/hip_runtime.h>

#define DIM 128
#define SCAN_BLK 1024

// round-to-nearest-even f32 -> bf16 bits
__device__ __forceinline__ unsigned short bf16rn(float f) {
    unsigned u = __float_as_uint(f);
    u += 0x7fffu + ((u >> 16) & 1u);
    return (unsigned short)(u >> 16);
}

// ---- per-node dot + bf16 row conversion; also zeroes cnt (replaces memset) ----
__global__ void k_prep(const float* __restrict__ u_emb, const float* __restrict__ i_emb,
                       const float* __restrict__ attn_w, float* __restrict__ sdot,
                       ushort2* __restrict__ bemb, unsigned* __restrict__ cnt,
                       int nu, int n, int do_bf16) {
    int tid = blockIdx.x * blockDim.x + threadIdx.x;
    if (tid < n) cnt[tid] = 0u;              // grid has >= n threads (64 per node)
    int gw = tid >> 6;
    int lane = threadIdx.x & 63;
    if (gw >= n) return;
    const bool isU = gw < nu;
    const float2* row = (const float2*)(isU ? u_emb + (size_t)gw * DIM
                                            : i_emb + (size_t)(gw - nu) * DIM);
    const float2* wv  = (const float2*)(isU ? attn_w : attn_w + DIM);
    float2 a = row[lane];
    float2 b = wv[lane];
    float v = a.x * b.x + a.y * b.y;
    #pragma unroll
    for (int off = 32; off; off >>= 1) v += __shfl_down(v, off);
    if (lane == 0) sdot[gw] = v;
    if (do_bf16) {
        ushort2 h;
        h.x = bf16rn(a.x);
        h.y = bf16rn(a.y);
        bemb[(size_t)gw * (DIM / 2) + lane] = h;
    }
}

// ---- per-edge degree histogram; atomic return value = rank within node list ----
__global__ void k_count(const int* __restrict__ uidx, const int* __restrict__ iidx,
                        unsigned* __restrict__ cnt, unsigned* __restrict__ ranks,
                        int nu, int ne) {
    int e = blockIdx.x * blockDim.x + threadIdx.x;
    if (e >= ne) return;
    unsigned r0 = atomicAdd(&cnt[uidx[e]], 1u);
    unsigned r1 = atomicAdd(&cnt[nu + iidx[e]], 1u);
    ranks[e] = (r0 << 16) | (r1 & 0xffffu);
}

// ---- two-level scan ----
__global__ void k_scan1(const unsigned* __restrict__ cnt, unsigned* __restrict__ incl,
                        unsigned* __restrict__ bsum, int n) {
    __shared__ unsigned part[SCAN_BLK];
    int t = threadIdx.x;
    int j = blockIdx.x * SCAN_BLK + t;
    unsigned v = (j < n) ? cnt[j] : 0u;
    part[t] = v;
    __syncthreads();
    for (int d = 1; d < SCAN_BLK; d <<= 1) {
        unsigned w = (t >= d) ? part[t - d] : 0u;
        __syncthreads();
        part[t] += w;
        __syncthreads();
    }
    if (j < n) incl[j] = part[t];
    if (t == SCAN_BLK - 1) bsum[blockIdx.x] = part[t];
}

__global__ void k_scan2(unsigned* __restrict__ bsum, int nb) {
    __shared__ unsigned part[SCAN_BLK];
    int t = threadIdx.x;
    unsigned v = (t < nb) ? bsum[t] : 0u;
    part[t] = v;
    __syncthreads();
    for (int d = 1; d < SCAN_BLK; d <<= 1) {
        unsigned w = (t >= d) ? part[t - d] : 0u;
        __syncthreads();
        part[t] += w;
        __syncthreads();
    }
    if (t < nb) bsum[t] = part[t] - v;   // exclusive prefix
}

__global__ void k_scan3(const unsigned* __restrict__ cnt, const unsigned* __restrict__ incl,
                        const unsigned* __restrict__ bsum,
                        unsigned* __restrict__ off, int n) {
    int j = blockIdx.x * blockDim.x + threadIdx.x;
    if (j >= n) return;
    off[j] = incl[j] - cnt[j] + bsum[j / SCAN_BLK];
}

// ---- per-edge CSR fill: neighbor CONCAT index, rank-addressed (no atomics) ----
__global__ void k_fill(const int* __restrict__ uidx, const int* __restrict__ iidx,
                       const unsigned* __restrict__ off, const unsigned* __restrict__ ranks,
                       int* __restrict__ nbr, int nu, int ne) {
    int e = blockIdx.x * blockDim.x + threadIdx.x;
    if (e >= ne) return;
    int u = uidx[e], i = iidx[e];
    unsigned rk = ranks[e];
    nbr[off[u]      + (rk >> 16)]     = nu + i;
    nbr[off[nu + i] + (rk & 0xffffu)] = u;
}

// ---- persistent-wave accum, broadcast-free quad gathers:
// quad q handles neighbors j = q, q+4, ... ; its 16 lanes read nbr[s+j] and
// sdot[o] at the SAME address (HW broadcast, no ds_bpermute), and the w=exp()
// is recomputed per quad (trans pipe is idle). The 256B bemb gather depends
// only on o, so the sdot load + exp hide under it. No chunking, no tail code.
__global__ void k_accum_bf16(const float* __restrict__ u_emb, const float* __restrict__ i_emb,
                             const uint4* __restrict__ bemb, const float* __restrict__ sdot,
                             const unsigned* __restrict__ off, const unsigned* __restrict__ cnt,
                             const int* __restrict__ nbr,
                             float* __restrict__ out, int nu, int n) {
    int wid  = (blockIdx.x * blockDim.x + threadIdx.x) >> 6;
    int lane = threadIdx.x & 63;
    int nwav = (gridDim.x * blockDim.x) >> 6;
    int q = lane >> 4, l16 = lane & 15;

    for (int node = wid; node < n; node += nwav) {
        unsigned s = off[node];
        unsigned d = cnt[node];
        float ss = sdot[node];

        float acc[8] = {0.f, 0.f, 0.f, 0.f, 0.f, 0.f, 0.f, 0.f};
        float wsum = 0.f;

        #pragma unroll 2
        for (unsigned j = (unsigned)q; j < d; j += 4) {
            int o = nbr[s + j];                       // 16 lanes, same addr (L1 bcast)
            uint4 h = bemb[(size_t)o * (DIM / 8) + l16];  // 256B row gather
            float r = ss + sdot[o];                   // hides under the gather
            r = fmaxf(r, 0.2f * r);                   // leaky relu, branchless
            float w = __expf(r);                      // raw ~ N(0,1): no max shift
            wsum += w;
            acc[0] += w * __uint_as_float(h.x << 16);
            acc[1] += w * __uint_as_float(h.x & 0xffff0000u);
            acc[2] += w * __uint_as_float(h.y << 16);
            acc[3] += w * __uint_as_float(h.y & 0xffff0000u);
            acc[4] += w * __uint_as_float(h.z << 16);
            acc[5] += w * __uint_as_float(h.z & 0xffff0000u);
            acc[6] += w * __uint_as_float(h.w << 16);
            acc[7] += w * __uint_as_float(h.w & 0xffff0000u);
        }

        // combine the 4 quarter-wave partials (each neighbor counted by 1 quad)
        #pragma unroll
        for (int m = 16; m <= 32; m <<= 1) {
            wsum += __shfl_xor(wsum, m);
            #pragma unroll
            for (int k = 0; k < 8; ++k) acc[k] += __shfl_xor(acc[k], m);
        }

        if (q == 0) {
            float inv = 1.f / (wsum + 1e-10f);
            const float* self = (node < nu) ? u_emb + (size_t)node * DIM
                                            : i_emb + (size_t)(node - nu) * DIM;
            const float4* sr = (const float4*)self;
            float4 s0 = sr[2 * l16];
            float4 s1 = sr[2 * l16 + 1];
            s0.x += acc[0] * inv; s0.y += acc[1] * inv;
            s0.z += acc[2] * inv; s0.w += acc[3] * inv;
            s1.x += acc[4] * inv; s1.y += acc[5] * inv;
            s1.z += acc[6] * inv; s1.w += acc[7] * inv;
            float4* orow = (float4*)(out + (size_t)node * DIM);
            orow[2 * l16]     = s0;
            orow[2 * l16 + 1] = s1;
        }
    }
}

// ---- fallback (no bf16 scratch): float2-per-lane, f32 gathers, CSR layout ----
__global__ void k_accum_f32(const float* __restrict__ u_emb, const float* __restrict__ i_emb,
                            const float* __restrict__ sdot,
                            const unsigned* __restrict__ off, const unsigned* __restrict__ cnt,
                            const int* __restrict__ nbr,
                            float* __restrict__ out, int nu, int n) {
    int gw = (blockIdx.x * blockDim.x + threadIdx.x) >> 6;
    int lane = threadIdx.x & 63;
    if (gw >= n) return;
    float sd_self = sdot[gw];
    unsigned s = off[gw];
    unsigned d = cnt[gw];
    float2 acc = make_float2(0.f, 0.f);
    float wsum = 0.f;
    for (unsigned base = 0; base < d; base += 64) {
        unsigned chunk = d - base; if (chunk > 64) chunk = 64;
        int   o = 0;
        float w = 0.f;
        if (lane < (int)chunk) {
            o = nbr[s + base + lane];
            float r = sd_self + sdot[o];
            r = fmaxf(r, 0.2f * r);
            w = __expf(r);
        }
        for (unsigned j = 0; j < chunk; ++j) {
            int   oj = __shfl(o, (int)j);
            float wj = __shfl(w, (int)j);
            const float* base_ = (oj < nu) ? u_emb + (size_t)oj * DIM
                                           : i_emb + (size_t)(oj - nu) * DIM;
            float2 vj = ((const float2*)base_)[lane];
            wsum += wj;
            acc.x += wj * vj.x;
            acc.y += wj * vj.y;
        }
    }
    float inv = 1.f / (wsum + 1e-10f);
    const float* self = (gw < nu) ? u_emb + (size_t)gw * DIM
                                  : i_emb + (size_t)(gw - nu) * DIM;
    float2 sv = ((const float2*)self)[lane];
    sv.x += acc.x * inv;
    sv.y += acc.y * inv;
    ((float2*)(out + (size_t)gw * DIM))[lane] = sv;
}

extern "C" void kernel_launch(void* const* d_in, const int* in_sizes, int n_in,
                              void* d_out, int out_size, void* d_ws, size_t ws_size,
                              hipStream_t stream) {
    const float* u_emb  = (const float*)d_in[0];
    const float* i_emb  = (const float*)d_in[1];
    const int*   edge   = (const int*)d_in[2];
    // d_in[3] = weights, unused by the reference
    const float* attn_w = (const float*)d_in[4];

    const int nu = in_sizes[0] / DIM;
    const int ni = in_sizes[1] / DIM;
    const int ne = in_sizes[3];
    const int n  = nu + ni;

    const int* uidx = edge;
    const int* iidx = edge + ne;

    float* out = (float*)d_out;   // rows [0,nu) = new_u, rows [nu,n) = new_i

    char* ws = (char*)d_ws;
    size_t used = 0;
    auto take = [&](size_t bytes) {
        char* p = ws + used;
        used += (bytes + 15) & ~size_t(15);
        return p;
    };
    float*    sdot  = (float*)   take((size_t)n * sizeof(float));
    unsigned* cnt   = (unsigned*)take((size_t)n * sizeof(unsigned));
    unsigned* off   = (unsigned*)take((size_t)n * sizeof(unsigned));
    unsigned* incl  = (unsigned*)take((size_t)n * sizeof(unsigned));
    unsigned* bsum  = (unsigned*)take((size_t)SCAN_BLK * sizeof(unsigned));
    unsigned* ranks = (unsigned*)take((size_t)ne * sizeof(unsigned));
    int*      nbr   = (int*)     take((size_t)2 * ne * sizeof(int));
    size_t bembBytes = (size_t)n * DIM * 2;          // bf16 concat table (38.4 MB)
    const int do_bf16 = (used + bembBytes <= ws_size) ? 1 : 0;
    void* bemb = do_bf16 ? (void*)take(bembBytes) : nullptr;

    const int nb = (n + SCAN_BLK - 1) / SCAN_BLK;   // 147 for n=150k

    // 1. prep: per-node dots + bf16 conversion + cnt zeroing (streaming)
    k_prep<<<(n + 3) / 4, 256, 0, stream>>>(u_emb, i_emb, attn_w, sdot,
                                            (ushort2*)bemb, cnt, nu, n, do_bf16);

    // 2. degree histogram with per-edge ranks (L2-resident atomics, isolated)
    k_count<<<(ne + 255) / 256, 256, 0, stream>>>(uidx, iidx, cnt, ranks, nu, ne);

    // 3. CSR offsets via two-level scan
    k_scan1<<<nb, SCAN_BLK, 0, stream>>>(cnt, incl, bsum, n);
    k_scan2<<<1, SCAN_BLK, 0, stream>>>(bsum, nb);
    k_scan3<<<(n + 255) / 256, 256, 0, stream>>>(cnt, incl, bsum, off, n);

    // 4. CSR fill at off+rank (no atomics; isolated from streaming)
    k_fill<<<(ne + 255) / 256, 256, 0, stream>>>(uidx, iidx, off, ranks, nbr, nu, ne);

    // 5. gather-accumulate: persistent waves, broadcast-free quad gathers
    if (do_bf16)
        k_accum_bf16<<<2048, 256, 0, stream>>>(u_emb, i_emb, (const uint4*)bemb,
                                               sdot, off, cnt, nbr, out, nu, n);
    else
        k_accum_f32<<<(n + 3) / 4, 256, 0, stream>>>(u_emb, i_emb, sdot, off, cnt,
                                                     nbr, out, nu, n);
}